// Round 12
// baseline (52.985 us; speedup 1.0000x reference)
//
#include <hip/hip_runtime.h>

// Depth-4 path signature, C=10, L=64, B=2048 — MFMA formulation (R12).
// Closed form (validated R8-R11, absmax 5.25 vs thr 12.16):
//   P_t = exclusive prefix of dx;  R_t[l] = S1[l] - P_{t+1}[l]
//   z_t[ij] = (P_t[i]+di/2)*dj ; s2_t = exclusive-prefix_t(z)  (s2_63 = S2)
//   u2_t = (P_t[i]+di/4)*dj/3 + s2_t ; v2_t = (P_t[i]+di/3)*dj/2 + s2_t
//   S4[ij,kl] = sum_t v2_t*(dx_t[k]*R_t[l]) + sum_t u2_t*(dx_t[k]*dx_t[l]/2)
//   S3[ij,k]  = sum_t v2_t*dx_t[k]
// One K=128 GEMM/elem: A(100x128)=[V2|U2], B(110x128)=[dx ox R | dx ; dx ox dx/2 | 0].
// R12 vs R11 (46us): (1) 512-thr blocks -> 16 waves/CU at 2 blocks/CU
// (R11: 8 waves, occ 19%, latency-bound with all pipes idle);
// (2) A-build de-serialized: s2 chain = prefix scan of z (shfl_up over
// t-on-lanes), one row per wave per iteration, all 8 waves busy
// (R11: 63-step serial chain on 2 waves, 6 idle).
// LDS layout/swizzle unchanged: KS=128 shorts (256B row, == 0 mod 128B),
// 16B-granule XOR swz -> conflict-free b128 column-writes and k-reads.

typedef short short8 __attribute__((ext_vector_type(8)));
typedef float f32x4 __attribute__((ext_vector_type(4)));
typedef unsigned int uint4v __attribute__((ext_vector_type(4)));

constexpr int C = 10, L = 64, T = 63;          // T = L-1 steps
constexpr int OUTSZ = 10 + 100 + 1000 + 10000; // 11110
constexpr int DXP = 13;                        // dx/P row stride (fp32 words)
constexpr int KS = 128;                        // A/B row stride in shorts (256B)

__device__ __forceinline__ unsigned short f2bf(float f) {  // RNE f32->bf16
  unsigned u = __float_as_uint(f);
  return (unsigned short)((u + 0x7FFFu + ((u >> 16) & 1u)) >> 16);
}
__device__ __forceinline__ int swz(int row, int k) {  // short idx, 16B-granule XOR
  return row * KS + ((((k >> 3) ^ (row & 7)) << 3) | (k & 7));
}

__global__ __launch_bounds__(512, 4) void sig4_kernel(
    const float* __restrict__ x, float* __restrict__ out)
{
  __shared__ __align__(16) unsigned short Ab[100 * KS];  // 25.6 KB
  __shared__ __align__(16) unsigned short Bb[110 * KS];  // 28.2 KB
  __shared__ float dxs[T * DXP];                         // 3.3 KB
  __shared__ float Ps[64 * DXP];                         // 3.3 KB

  const int t = threadIdx.x;
  const int w = t >> 6, lane = t & 63;
  const float* __restrict__ xb = x + (size_t)blockIdx.x * (C * L);
  float* __restrict__ ob = out + (size_t)blockIdx.x * OUTSZ;

  // ---- phase A: path -> dx, exclusive prefix P (shuffle scan) ----
  float* pl = (float*)Bb;  // alias: Bb first written in phase B (after last pl read)
  for (int i = t; i < C * L; i += 512) pl[i] = xb[i];
  __syncthreads();
  for (int i = t; i < T * C; i += 512) {
    int s = i / C, c = i - s * C;
    dxs[s * DXP + c] = pl[c * L + s + 1] - pl[c * L + s];
  }
  __syncthreads();
  for (int c = w; c < C; c += 8) {
    float v = (lane > 0) ? dxs[(lane - 1) * DXP + c] : 0.f;
    #pragma unroll
    for (int d = 1; d < 64; d <<= 1) {
      float y = __shfl_up(v, d);
      if (lane >= d) v += y;
    }
    Ps[lane * DXP + c] = v;   // P[t][c] = sum_{s<t} dx_s[c]; P[63] = S1
  }
  __syncthreads();

  // ---- phase B1: A-build — one row per wave per iter, scan over t-on-lanes ----
  for (int it = 0; it < 13; ++it) {
    const int r = w + 8 * it;               // rows 0..103, guard <100
    if (r < 100) {
      const int i_ = r / 10, j_ = r - (r / 10) * 10;
      float di = 0.f, dj = 0.f, p = 0.f;
      if (lane < T) {
        di = dxs[lane * DXP + i_];
        dj = dxs[lane * DXP + j_];
        p  = Ps[lane * DXP + i_];
      }
      float z = fmaf(di, 0.5f, p) * dj;     // lane >= 63: 0
      float incl = z;
      #pragma unroll
      for (int d = 1; d < 64; d <<= 1) {
        float y = __shfl_up(incl, d);
        if (lane >= d) incl += y;
      }
      const float s2x = incl - z;           // exclusive prefix = s2_t
      float u2 = 0.f, v2 = 0.f;
      if (lane < T) {
        u2 = fmaf(fmaf(di, 0.25f, p), dj * (1.f / 3.f), s2x);
        v2 = fmaf(fmaf(di, (1.f / 3.f), p), dj * 0.5f, s2x);
      }
      Ab[swz(r, lane)]      = f2bf(v2);     // k-slot 63 zeroed via guard
      Ab[swz(r, 64 + lane)] = f2bf(u2);     // k-slot 127 zeroed via guard
      if (lane == 63) ob[10 + r] = s2x;     // S2 (fp32 tree sum)
    }
  }
  if (t < 10) ob[t] = Ps[63 * DXP + t];     // S1

  // ---- phase B2: B-build over all 512 lanes ----
  for (int task = t; task < 110 * 8; task += 512) {  // (col, k-chunk) tasks
    const int col = task >> 3, ch = task & 7;
    unsigned b1pk[4], b2pk[4];
    if (col < 100) {
      const int k2 = col / 10, l2 = col - k2 * 10;
      const float S1l = Ps[63 * DXP + l2];
      #pragma unroll
      for (int e = 0; e < 8; ++e) {
        const int kk = ch * 8 + e;
        float b1 = 0.f, b2 = 0.f;
        if (kk < T) {
          float d  = dxs[kk * DXP + k2];
          float dl = dxs[kk * DXP + l2];
          float R  = S1l - Ps[(kk + 1) * DXP + l2];
          b1 = d * R;
          b2 = d * dl * 0.5f;
        }
        unsigned x1 = f2bf(b1), x2 = f2bf(b2);
        if ((e & 1) == 0) { b1pk[e >> 1] = x1; b2pk[e >> 1] = x2; }
        else             { b1pk[e >> 1] |= x1 << 16; b2pk[e >> 1] |= x2 << 16; }
      }
    } else {
      const int c2 = col - 100;
      #pragma unroll
      for (int e = 0; e < 8; ++e) {
        const int kk = ch * 8 + e;
        float b1 = (kk < T) ? dxs[kk * DXP + c2] : 0.f;
        unsigned x1 = f2bf(b1);
        if ((e & 1) == 0) { b1pk[e >> 1] = x1; b2pk[e >> 1] = 0u; }
        else             { b1pk[e >> 1] |= x1 << 16; }
      }
    }
    *(uint4v*)&Bb[swz(col, ch * 8)]      = uint4v{b1pk[0], b1pk[1], b1pk[2], b1pk[3]};
    *(uint4v*)&Bb[swz(col, 64 + ch * 8)] = uint4v{b2pk[0], b2pk[1], b2pk[2], b2pk[3]};
  }
  __syncthreads();

  // ---- phase C: GEMM C(100x110) = A(100x128) x B(128x110), one rt per wave ----
  if (w < 7) {
    const int lm = lane & 15, lg = lane >> 4;
    const int rt = w;
    const int arow = rt * 16 + lm;
    short8 a[4];
    #pragma unroll
    for (int ks = 0; ks < 4; ++ks)
      a[ks] = (arow < 100) ? *(const short8*)&Ab[swz(arow, ks * 32 + lg * 8)]
                           : short8{0, 0, 0, 0, 0, 0, 0, 0};
    for (int ct = 0; ct < 7; ++ct) {
      const int bcol = ct * 16 + lm;
      f32x4 acc = {0.f, 0.f, 0.f, 0.f};
      #pragma unroll
      for (int ks = 0; ks < 4; ++ks) {
        short8 bf = (bcol < 110)
            ? *(const short8*)&Bb[swz(bcol, ks * 32 + lg * 8)]
            : short8{0, 0, 0, 0, 0, 0, 0, 0};
        acc = __builtin_amdgcn_mfma_f32_16x16x32_bf16(a[ks], bf, acc, 0, 0, 0);
      }
      const int rbase = rt * 16 + lg * 4;
      #pragma unroll
      for (int r = 0; r < 4; ++r) {
        const int row = rbase + r;
        if (row < 100) {
          if (bcol < 100)      ob[1110 + row * 100 + bcol] = acc[r];
          else if (bcol < 110) ob[110 + row * 10 + (bcol - 100)] = acc[r];
        }
      }
    }
  }
}

extern "C" void kernel_launch(void* const* d_in, const int* in_sizes, int n_in,
                              void* d_out, int out_size, void* d_ws, size_t ws_size,
                              hipStream_t stream) {
  const float* x = (const float*)d_in[0];
  float* out = (float*)d_out;
  const int batch = in_sizes[0] / (C * L);   // 2048
  sig4_kernel<<<dim3(batch), dim3(512), 0, stream>>>(x, out);
}

// Round 13
// 38.719 us; speedup vs baseline: 1.3685x; 1.3685x over previous
//
#include <hip/hip_runtime.h>

// Depth-4 path signature, C=10, L=64, B=2048 — MFMA formulation (R13).
// Closed form (validated R8-R12, absmax 5.25 vs thr 12.16):
//   P_t = exclusive prefix of dx;  R_t[l] = S1[l] - P_{t+1}[l]
//   per (i,j): s2 serial Horner chain; u2_t, v2_t level-2 scalars
//   S4[ij,kl] = sum_t v2_t*(dx_t[k]*R_t[l]) + sum_t u2_t*(dx_t[k]*dx_t[l]/2)
//   S3[ij,k]  = sum_t v2_t*dx_t[k]
// R13 vs R11 (best, 46us): two K=64 passes to shrink LDS 60.4 -> 33.5 KB
// (2 -> 4 blocks/CU; R11 was latency-bound with ALL pipes <30%), WITHOUT
// R10's doubled serial build: U2 is computed in the single chain and
// carried bf16-packed in 32 VGPRs, written to Ab after pass-0 GEMM.
//   pass 0: A=V2(100x64), B=[dx ox R | dx](110x64)  -> S4 part 1 + S3
//   pass 1: A=U2,         B=[dx ox dx /2 | 0]       -> S4 part 2
// Also: B-fragment register reuse across the 2 rt-strips (GEMM LDS reads
// 32 -> 18 b128/wave/pass). Swizzle unchanged (KS=64 shorts = 128B row
// stride == 0 mod 128B; granule = (k>>3)^(row&7) permutes bank-groups).

typedef short short8 __attribute__((ext_vector_type(8)));
typedef float f32x4 __attribute__((ext_vector_type(4)));
typedef unsigned int uint4v __attribute__((ext_vector_type(4)));

constexpr int C = 10, L = 64, T = 63;          // T = L-1 steps
constexpr int OUTSZ = 10 + 100 + 1000 + 10000; // 11110
constexpr int DXP = 13;                        // dx/P row stride (fp32 words)
constexpr int KS = 64;                         // per-pass row stride in shorts (128B)

__device__ __forceinline__ unsigned short f2bf(float f) {  // RNE f32->bf16
  unsigned u = __float_as_uint(f);
  return (unsigned short)((u + 0x7FFFu + ((u >> 16) & 1u)) >> 16);
}
__device__ __forceinline__ int swz(int row, int k) {  // short idx, 16B-granule XOR
  return row * KS + ((((k >> 3) ^ (row & 7)) << 3) | (k & 7));
}

__global__ __launch_bounds__(256, 4) void sig4_kernel(
    const float* __restrict__ x, float* __restrict__ out)
{
  __shared__ __align__(16) unsigned short Ab[100 * KS];  // 12.8 KB
  __shared__ __align__(16) unsigned short Bb[110 * KS];  // 14.1 KB
  __shared__ float dxs[T * DXP];                         // 3.3 KB
  __shared__ float Ps[64 * DXP];                         // 3.3 KB

  const int t = threadIdx.x;
  const float* __restrict__ xb = x + (size_t)blockIdx.x * (C * L);
  float* __restrict__ ob = out + (size_t)blockIdx.x * OUTSZ;

  // ---- phase A: path -> dx, exclusive prefix P (shuffle scan) ----
  float* pl = (float*)Bb;  // alias: Bb first written in build (after last pl read)
  for (int i = t; i < C * L; i += 256) pl[i] = xb[i];
  __syncthreads();
  for (int i = t; i < T * C; i += 256) {
    int s = i / C, c = i - s * C;
    dxs[s * DXP + c] = pl[c * L + s + 1] - pl[c * L + s];
  }
  __syncthreads();
  {
    int w0 = t >> 6, lane0 = t & 63;
    for (int c = w0; c < C; c += 4) {
      float v = (lane0 > 0) ? dxs[(lane0 - 1) * DXP + c] : 0.f;
      #pragma unroll
      for (int d = 1; d < 64; d <<= 1) {
        float y = __shfl_up(v, d);
        if (lane0 >= d) v += y;
      }
      Ps[lane0 * DXP + c] = v;  // P[t][c] = sum_{s<t} dx_s[c]; P[63] = S1
    }
  }
  __syncthreads();

  unsigned u2r[32];  // U2 bf16-packed (64 slots; slot 63 zero), static-indexed

  // ---- build pass 0: A=V2 (lanes 0..99) || B=[dx ox R | dx] (lanes 128..255) ----
  if (t < 100) {
    const int i_ = t / 10, j_ = t - (t / 10) * 10;
    float s2 = 0.f;
    #pragma unroll
    for (int ch = 0; ch < 8; ++ch) {
      unsigned vpk[4];
      #pragma unroll
      for (int e = 0; e < 8; ++e) {
        const int s = ch * 8 + e;
        float u2 = 0.f, v2 = 0.f;
        if (s < T) {
          float di = dxs[s * DXP + i_];
          float dj = dxs[s * DXP + j_];
          float p  = Ps[s * DXP + i_];
          u2 = fmaf(fmaf(di, 0.25f, p), dj * (1.f / 3.f), s2);
          v2 = fmaf(fmaf(di, (1.f / 3.f), p), dj * 0.5f, s2);
          s2 = fmaf(fmaf(di, 0.5f, p), dj, s2);
        }
        unsigned vb = f2bf(v2), ub = f2bf(u2);
        if ((e & 1) == 0) { vpk[e >> 1] = vb;        u2r[ch * 4 + (e >> 1)] = ub; }
        else             { vpk[e >> 1] |= vb << 16;  u2r[ch * 4 + (e >> 1)] |= ub << 16; }
      }
      *(uint4v*)&Ab[swz(t, ch * 8)] = uint4v{vpk[0], vpk[1], vpk[2], vpk[3]};
    }
    ob[10 + t] = s2;                            // S2 (exact fp32)
    if (j_ == 0) ob[i_] = Ps[63 * DXP + i_];    // S1
  } else if (t >= 128) {
    const int q = t - 128;
    for (int task = q; task < 110 * 8; task += 128) {
      const int col = task >> 3, ch = task & 7;
      unsigned pk[4];
      if (col < 100) {
        const int k2 = col / 10, l2 = col - (col / 10) * 10;
        const float S1l = Ps[63 * DXP + l2];
        #pragma unroll
        for (int e = 0; e < 8; ++e) {
          const int kk = ch * 8 + e;
          float b1 = 0.f;
          if (kk < T) {
            float d = dxs[kk * DXP + k2];
            b1 = d * (S1l - Ps[(kk + 1) * DXP + l2]);
          }
          unsigned x1 = f2bf(b1);
          if ((e & 1) == 0) pk[e >> 1] = x1; else pk[e >> 1] |= x1 << 16;
        }
      } else {
        const int c2 = col - 100;
        #pragma unroll
        for (int e = 0; e < 8; ++e) {
          const int kk = ch * 8 + e;
          float b1 = (kk < T) ? dxs[kk * DXP + c2] : 0.f;
          unsigned x1 = f2bf(b1);
          if ((e & 1) == 0) pk[e >> 1] = x1; else pk[e >> 1] |= x1 << 16;
        }
      }
      *(uint4v*)&Bb[swz(col, ch * 8)] = uint4v{pk[0], pk[1], pk[2], pk[3]};
    }
  }
  __syncthreads();

  const int w = t >> 6, lane = t & 63;
  const int lm = lane & 15, lg = lane >> 4;

  f32x4 acc[2][7];
  #pragma unroll
  for (int rti = 0; rti < 2; ++rti)
    #pragma unroll
    for (int ct = 0; ct < 7; ++ct) acc[rti][ct] = f32x4{0.f, 0.f, 0.f, 0.f};

  // ---- GEMM helper pattern (B reused across both rt strips) ----
  #define GEMM_PASS()                                                          \
    do {                                                                       \
      short8 afr[2][2];                                                        \
      _Pragma("unroll")                                                        \
      for (int rti = 0; rti < 2; ++rti) {                                      \
        const int rt = w + rti * 4;                                            \
        const int arow = rt * 16 + lm;                                         \
        _Pragma("unroll")                                                      \
        for (int ks = 0; ks < 2; ++ks)                                         \
          afr[rti][ks] = (rt < 7 && arow < 100)                                \
              ? *(const short8*)&Ab[swz(arow, ks * 32 + lg * 8)]               \
              : short8{0, 0, 0, 0, 0, 0, 0, 0};                                \
      }                                                                        \
      for (int ct = 0; ct < 7; ++ct) {                                         \
        const int bcol = ct * 16 + lm;                                         \
        short8 b0 = (bcol < 110) ? *(const short8*)&Bb[swz(bcol, lg * 8)]      \
                                 : short8{0, 0, 0, 0, 0, 0, 0, 0};             \
        short8 b1 = (bcol < 110) ? *(const short8*)&Bb[swz(bcol, 32 + lg * 8)] \
                                 : short8{0, 0, 0, 0, 0, 0, 0, 0};             \
        _Pragma("unroll")                                                      \
        for (int rti = 0; rti < 2; ++rti) {                                    \
          if (w + rti * 4 < 7) {                                               \
            acc[rti][ct] = __builtin_amdgcn_mfma_f32_16x16x32_bf16(            \
                afr[rti][0], b0, acc[rti][ct], 0, 0, 0);                       \
            acc[rti][ct] = __builtin_amdgcn_mfma_f32_16x16x32_bf16(            \
                afr[rti][1], b1, acc[rti][ct], 0, 0, 0);                       \
          }                                                                    \
        }                                                                      \
      }                                                                        \
    } while (0)

  GEMM_PASS();   // pass 0: V2 x [dx ox R | dx]
  __syncthreads();

  // ---- build pass 1: A=U2 from registers || B=[dx ox dx /2 | 0] ----
  if (t < 100) {
    #pragma unroll
    for (int ch = 0; ch < 8; ++ch)
      *(uint4v*)&Ab[swz(t, ch * 8)] = uint4v{u2r[ch * 4], u2r[ch * 4 + 1],
                                             u2r[ch * 4 + 2], u2r[ch * 4 + 3]};
  } else if (t >= 128) {
    const int q = t - 128;
    for (int task = q; task < 110 * 8; task += 128) {
      const int col = task >> 3, ch = task & 7;
      unsigned pk[4] = {0u, 0u, 0u, 0u};
      if (col < 100) {
        const int k2 = col / 10, l2 = col - (col / 10) * 10;
        #pragma unroll
        for (int e = 0; e < 8; ++e) {
          const int kk = ch * 8 + e;
          float b2 = (kk < T) ? dxs[kk * DXP + k2] * dxs[kk * DXP + l2] * 0.5f : 0.f;
          unsigned x2 = f2bf(b2);
          if ((e & 1) == 0) pk[e >> 1] = x2; else pk[e >> 1] |= x2 << 16;
        }
      }
      *(uint4v*)&Bb[swz(col, ch * 8)] = uint4v{pk[0], pk[1], pk[2], pk[3]};
    }
  }
  __syncthreads();

  GEMM_PASS();   // pass 1: U2 x [dx ox dx /2 | 0], accumulates

  // ---- epilogue: write C from registers ----
  #pragma unroll
  for (int rti = 0; rti < 2; ++rti) {
    const int rt = w + rti * 4;
    if (rt < 7) {
      const int rbase = rt * 16 + lg * 4;
      #pragma unroll
      for (int ct = 0; ct < 7; ++ct) {
        const int bcol = ct * 16 + lm;
        #pragma unroll
        for (int r = 0; r < 4; ++r) {
          const int row = rbase + r;
          if (row < 100) {
            if (bcol < 100)      ob[1110 + row * 100 + bcol] = acc[rti][ct][r];
            else if (bcol < 110) ob[110 + row * 10 + (bcol - 100)] = acc[rti][ct][r];
          }
        }
      }
    }
  }
}

extern "C" void kernel_launch(void* const* d_in, const int* in_sizes, int n_in,
                              void* d_out, int out_size, void* d_ws, size_t ws_size,
                              hipStream_t stream) {
  const float* x = (const float*)d_in[0];
  float* out = (float*)d_out;
  const int batch = in_sizes[0] / (C * L);   // 2048
  sig4_kernel<<<dim3(batch), dim3(256), 0, stream>>>(x, out);
}